// Round 11
// baseline (1596.063 us; speedup 1.0000x reference)
//
#include <hip/hip_runtime.h>
#include <math.h>

#define D_ 1024
#define H_ 16
#define HD_ 64
#define L_ 8
#define V_ 2048
#define FF_ 4096
#define WIN_ 256
#define B_ 2
#define S_ 1024
#define MAXCYC_ 16

typedef __attribute__((ext_vector_type(4))) float f32x4;
typedef __attribute__((ext_vector_type(8))) short s16x8;

__device__ __forceinline__ unsigned short f2bf(float f) {
  union { float f; unsigned int u; } v; v.f = f;
  unsigned int r = v.u + 0x7FFFu + ((v.u >> 16) & 1u);
  return (unsigned short)(r >> 16);
}

__device__ __forceinline__ float wave_sum(float v) {
  #pragma unroll
  for (int m = 1; m < 64; m <<= 1) v += __shfl_xor(v, m, 64);
  return v;
}

// async global->LDS, 16B per lane. dst wave-uniform base; HW writes dst+lane*16.
__device__ __forceinline__ void gload16(const unsigned short* g, unsigned short* lds) {
  __builtin_amdgcn_global_load_lds(
      (const __attribute__((address_space(1))) void*)g,
      (__attribute__((address_space(3))) void*)lds,
      16, 0, 0);
}

// ---------------- f32 -> bf16 convert, ALL weights, grid-stride ---------------
// dst (bf16 cache) is contiguous in the order q,k,v,o,w1,w2,w3,head.
__global__ __launch_bounds__(256) void cvt_all_kernel(
    const float* __restrict__ s0, const float* __restrict__ s1,
    const float* __restrict__ s2, const float* __restrict__ s3,
    const float* __restrict__ s4, const float* __restrict__ s5,
    const float* __restrict__ s6, const float* __restrict__ s7,
    unsigned short* __restrict__ dst)
{
  const long nq = (long)L_*D_*D_/8;      // 1,048,576 chunks of 8 elems
  const long nf = (long)L_*FF_*D_/8;     // 4,194,304
  const long nh = (long)V_*D_/8;         // 262,144
  const long tot = 4*nq + 3*nf + nh;
  const long stride = (long)gridDim.x * 256;
  for (long i = (long)blockIdx.x*256 + threadIdx.x; i < tot; i += stride) {
    const float* src;
    long off = i;
    if (off < nq)              { src = s0; }
    else if ((off -= nq) < nq) { src = s1; }
    else if ((off -= nq) < nq) { src = s2; }
    else if ((off -= nq) < nq) { src = s3; }
    else if ((off -= nq) < nf) { src = s4; }
    else if ((off -= nf) < nf) { src = s5; }
    else if ((off -= nf) < nf) { src = s6; }
    else { off -= nf;            src = s7; }
    const float4* s = (const float4*)src + off*2;
    float4 a = s[0], b = s[1];
    s16x8 o;
    o[0] = (short)f2bf(a.x); o[1] = (short)f2bf(a.y);
    o[2] = (short)f2bf(a.z); o[3] = (short)f2bf(a.w);
    o[4] = (short)f2bf(b.x); o[5] = (short)f2bf(b.y);
    o[6] = (short)f2bf(b.z); o[7] = (short)f2bf(b.w);
    *(s16x8*)(dst + i*8) = o;     // one 16B store
  }
}

// ---------------- conditioning ----------------------------------------------
__global__ __launch_bounds__(256) void cond_kernel(
    const int* mood, const int* raga, const int* taal,
    const float* tempo, const float* duration,
    const float* mood_emb, const float* raga_emb, const float* taal_emb,
    const float* tempo_w, const float* tempo_b, const float* dur_w, const float* dur_b,
    const float* proj_w, const float* proj_b, const float* ln_g, const float* ln_b,
    float* cond)
{
  int b = blockIdx.x;
  int t = threadIdx.x;
  __shared__ float feat[192];
  __shared__ float red[4];
  if (t < 64)        feat[t] = mood_emb[mood[b]*64 + t];
  else if (t < 128)  feat[t] = raga_emb[raga[b]*64 + (t-64)];
  else if (t < 160)  feat[t] = taal_emb[taal[b]*32 + (t-128)];
  else if (t < 176)  feat[t] = tempo[b]*tempo_w[t-160] + tempo_b[t-160];
  else if (t < 192)  feat[t] = duration[b]*dur_w[t-176] + dur_b[t-176];
  __syncthreads();
  float g[4];
  #pragma unroll
  for (int r = 0; r < 4; ++r) {
    int j = t + 256*r;
    const float* w = proj_w + (size_t)j*192;
    float acc = proj_b[j];
    for (int f = 0; f < 192; ++f) acc += feat[f]*w[f];
    g[r] = 0.5f * acc * (1.0f + erff(acc * 0.7071067811865475f));
  }
  int lane = t & 63, wv = t >> 6;
  float s1 = g[0]+g[1]+g[2]+g[3];
  s1 = wave_sum(s1);
  if (lane == 0) red[wv] = s1;
  __syncthreads();
  float mu = (red[0]+red[1]+red[2]+red[3]) * (1.0f/1024.0f);
  __syncthreads();
  float vs = 0.f;
  #pragma unroll
  for (int r = 0; r < 4; ++r) { float d = g[r]-mu; vs += d*d; }
  vs = wave_sum(vs);
  if (lane == 0) red[wv] = vs;
  __syncthreads();
  float var = (red[0]+red[1]+red[2]+red[3]) * (1.0f/1024.0f);
  float is = rsqrtf(var + 1e-5f);
  #pragma unroll
  for (int r = 0; r < 4; ++r) {
    int j = t + 256*r;
    cond[(size_t)b*D_ + j] = (g[r]-mu)*is*ln_g[j] + ln_b[j];
  }
}

// ---------------- embedding sum ----------------------------------------------
__global__ __launch_bounds__(256) void embed_kernel(
    const int* tokens, const float* tok_emb, const float* cond,
    const float* cycle_emb, const float* strength_emb, const int* tcl_p, float* x)
{
  int row = blockIdx.x;
  int b = row >> 10, s = row & 1023;
  int tcl = tcl_p[0];
  int cyc = tcl < MAXCYC_ ? tcl : MAXCYC_;
  int pr  = s % cyc;
  int str = (s % tcl == 0) ? 0 : 3;
  int tok = tokens[row];
  int d = threadIdx.x * 4;
  float4 a = *(const float4*)&tok_emb[(size_t)tok*D_ + d];
  float4 c = *(const float4*)&cond[(size_t)b*D_ + d];
  float4 p = *(const float4*)&cycle_emb[(size_t)pr*D_ + d];
  float4 e = *(const float4*)&strength_emb[(size_t)str*D_ + d];
  float4 o; o.x=a.x+c.x+p.x+e.x; o.y=a.y+c.y+p.y+e.y; o.z=a.z+c.z+p.z+e.z; o.w=a.w+c.w+p.w+e.w;
  *(float4*)&x[(size_t)row*D_ + d] = o;
}

// ---------------- rmsnorm -> bf16 --------------------------------------------
__global__ __launch_bounds__(256) void rmsnorm_kernel(
    const float* x, const float* w, unsigned short* out)
{
  int row = blockIdx.x;
  int t = threadIdx.x;
  __shared__ float red[4];
  const float* xr = x + (size_t)row*D_;
  float4 v = *(const float4*)&xr[t*4];
  float ss = v.x*v.x + v.y*v.y + v.z*v.z + v.w*v.w;
  ss = wave_sum(ss);
  int lane = t & 63, wv = t >> 6;
  if (lane == 0) red[wv] = ss;
  __syncthreads();
  float total = red[0]+red[1]+red[2]+red[3];
  float scale = rsqrtf(total * (1.0f/1024.0f) + 1e-5f);
  float4 wv4 = *(const float4*)&w[t*4];
  ushort4 o;
  o.x = f2bf(wv4.x * v.x * scale);
  o.y = f2bf(wv4.y * v.y * scale);
  o.z = f2bf(wv4.z * v.z * scale);
  o.w = f2bf(wv4.w * v.w * scale);
  *(ushort4*)&out[(size_t)row*D_ + t*4] = o;
}

// -------- fused: x += sum(partials); rmsnorm(x) -> bf16 -----------------------
__global__ __launch_bounds__(256) void resid_rmsnorm_kernel(
    float* __restrict__ x, const float* __restrict__ part, int nparts,
    const float* __restrict__ w, unsigned short* __restrict__ out)
{
  int row = blockIdx.x;
  int t = threadIdx.x;
  __shared__ float red[4];
  size_t base = (size_t)row*D_ + t*4;
  const size_t pstride = (size_t)B_*S_*D_;
  float4 v = *(const float4*)&x[base];
  for (int p = 0; p < nparts; ++p) {
    float4 a = *(const float4*)&part[p*pstride + base];
    v.x += a.x; v.y += a.y; v.z += a.z; v.w += a.w;
  }
  *(float4*)&x[base] = v;
  float ss = v.x*v.x + v.y*v.y + v.z*v.z + v.w*v.w;
  ss = wave_sum(ss);
  int lane = t & 63, wv = t >> 6;
  if (lane == 0) red[wv] = ss;
  __syncthreads();
  float total = red[0]+red[1]+red[2]+red[3];
  float scale = rsqrtf(total * (1.0f/1024.0f) + 1e-5f);
  float4 wv4 = *(const float4*)&w[t*4];
  ushort4 o;
  o.x = f2bf(wv4.x * v.x * scale);
  o.y = f2bf(wv4.y * v.y * scale);
  o.z = f2bf(wv4.z * v.z * scale);
  o.w = f2bf(wv4.w * v.w * scale);
  *(ushort4*)&out[(size_t)row*D_ + t*4] = o;
}

// ---------------- rope tables -------------------------------------------------
__global__ __launch_bounds__(256) void rope_table_kernel(float* costab, float* sintab)
{
  int i = blockIdx.x*256 + threadIdx.x;
  int s = i >> 6, d = i & 63;
  float inv = powf(10000.0f, -(float)(d & 31) * (1.0f/32.0f));
  float ang = (float)s * inv;
  float sn, cs;
  sincosf(ang, &sn, &cs);
  costab[i] = cs; sintab[i] = sn;
}

// =============== MFMA sliding-window flash attention (QBLK=64) =================
__global__ __launch_bounds__(256) void attn_mfma(
    const unsigned short* __restrict__ q, const unsigned short* __restrict__ k,
    const unsigned short* __restrict__ v, unsigned short* __restrict__ y)
{
  __shared__ unsigned short Ks[64*64];     // [key][d], 128B rows, chunk-swizzled
  __shared__ unsigned short VsT[64*72];    // [d][key], ld=72
  __shared__ unsigned short Ps[4*16*72];   // per-wave P / output tile

  int qb0 = blockIdx.x * 64;
  int h = blockIdx.y, b = blockIdx.z;
  int t = threadIdx.x, lane = t & 63, wv = t >> 6;
  int c = lane & 15, q4 = lane >> 4;
  unsigned short* Pw = &Ps[wv*16*72];

  s16x8 aq[2];
  {
    const unsigned short* qp =
        q + ((size_t)(b*S_ + qb0 + wv*16 + c)*D_ + h*HD_ + q4*8);
    aq[0] = *(const s16x8*)qp;
    aq[1] = *(const s16x8*)(qp + 32);
  }

  f32x4 o[4];
  #pragma unroll
  for (int j = 0; j < 4; ++j) o[j] = (f32x4){0.f,0.f,0.f,0.f};
  float m[4] = {-1e30f,-1e30f,-1e30f,-1e30f};
  float l[4] = {0.f,0.f,0.f,0.f};

  int skey = t >> 2;
  int scol = (t & 3) * 16;
  int kt0 = qb0 - 256; if (kt0 < 0) kt0 = 0;

  for (int kt = kt0; kt <= qb0; kt += 64) {
    __syncthreads();
    {
      const unsigned short* kp = k + ((size_t)(b*S_ + kt + skey)*D_ + h*HD_ + scol);
      s16x8 k0 = *(const s16x8*)kp;
      s16x8 k1 = *(const s16x8*)(kp + 8);
      int ch0 = scol >> 3;
      *(s16x8*)((char*)Ks + skey*128 + ((ch0 ^ (skey & 7)) << 4)) = k0;
      *(s16x8*)((char*)Ks + skey*128 + (((ch0+1) ^ (skey & 7)) << 4)) = k1;
      const unsigned short* vp = v + ((size_t)(b*S_ + kt + skey)*D_ + h*HD_ + scol);
      s16x8 v0 = *(const s16x8*)vp;
      s16x8 v1 = *(const s16x8*)(vp + 8);
      #pragma unroll
      for (int i = 0; i < 8; ++i) {
        VsT[(scol + i)*72 + skey]     = (unsigned short)v0[i];
        VsT[(scol + 8 + i)*72 + skey] = (unsigned short)v1[i];
      }
    }
    __syncthreads();

    f32x4 sa[4];
    #pragma unroll
    for (int j = 0; j < 4; ++j) sa[j] = (f32x4){0.f,0.f,0.f,0.f};
    __builtin_amdgcn_s_setprio(1);
    #pragma unroll
    for (int ks = 0; ks < 2; ++ks)
      #pragma unroll
      for (int j = 0; j < 4; ++j) {
        int key = j*16 + c;
        s16x8 bk = *(const s16x8*)((const char*)Ks + key*128 +
                                   (((q4 + ks*4) ^ (key & 7)) << 4));
        sa[j] = __builtin_amdgcn_mfma_f32_16x16x32_bf16(aq[ks], bk, sa[j], 0, 0, 0);
      }
    __builtin_amdgcn_s_setprio(0);

    float sv[4][4];
    #pragma unroll
    for (int j = 0; j < 4; ++j) {
      int kg = kt + j*16 + c;
      #pragma unroll
      for (int reg = 0; reg < 4; ++reg) {
        int qg = qb0 + wv*16 + q4*4 + reg;
        bool ok = (qg >= kg) && (qg - kg < WIN_);
        sv[j][reg] = ok ? sa[j][reg]*0.125f : -3e38f;
      }
    }
    #pragma unroll
    for (int reg = 0; reg < 4; ++reg) {
      float mx = fmaxf(fmaxf(sv[0][reg], sv[1][reg]), fmaxf(sv[2][reg], sv[3][reg]));
      #pragma unroll
      for (int msk = 1; msk < 16; msk <<= 1)
        mx = fmaxf(mx, __shfl_xor(mx, msk, 64));
      float nm = fmaxf(m[reg], mx);
      float f = __expf(m[reg] - nm);
      m[reg] = nm;
      l[reg] *= f;
      o[0][reg] *= f; o[1][reg] *= f; o[2][reg] *= f; o[3][reg] *= f;
      float ps = 0.f;
      #pragma unroll
      for (int j = 0; j < 4; ++j) {
        float p = __expf(sv[j][reg] - nm);
        ps += p;
        Pw[(q4*4 + reg)*72 + j*16 + c] = f2bf(p);
      }
      l[reg] += ps;
    }

    __builtin_amdgcn_s_setprio(1);
    #pragma unroll
    for (int ks = 0; ks < 2; ++ks) {
      s16x8 pa = *(const s16x8*)((const char*)Pw + c*144 + (q4 + ks*4)*16);
      #pragma unroll
      for (int j = 0; j < 4; ++j) {
        s16x8 bv = *(const s16x8*)((const char*)VsT + (j*16 + c)*144 + (q4 + ks*4)*16);
        o[j] = __builtin_amdgcn_mfma_f32_16x16x32_bf16(pa, bv, o[j], 0, 0, 0);
      }
    }
    __builtin_amdgcn_s_setprio(0);
  }

  float inv[4];
  #pragma unroll
  for (int reg = 0; reg < 4; ++reg) {
    float ll = l[reg];
    #pragma unroll
    for (int msk = 1; msk < 16; msk <<= 1) ll += __shfl_xor(ll, msk, 64);
    inv[reg] = 1.0f / ll;
  }
  #pragma unroll
  for (int j = 0; j < 4; ++j)
    #pragma unroll
    for (int reg = 0; reg < 4; ++reg)
      Pw[(q4*4 + reg)*72 + j*16 + c] = f2bf(o[j][reg] * inv[reg]);
  int lr = lane >> 2, cc = (lane & 3)*16;
  s16x8 y0 = *(const s16x8*)((const char*)Pw + lr*144 + cc*2);
  s16x8 y1 = *(const s16x8*)((const char*)Pw + lr*144 + cc*2 + 16);
  unsigned short* yp = y + ((size_t)(b*S_ + qb0 + wv*16 + lr)*D_ + h*HD_ + cc);
  *(s16x8*)yp = y0;
  *(s16x8*)(yp + 8) = y1;
}

// ===== fused W1/W3 GEMM: 128x128, BK=32, depth-2 pipeline, 2 barriers/step ====
__global__ __launch_bounds__(256, 2) void gemm_w13(
    const unsigned short* __restrict__ A,
    const unsigned short* __restrict__ W1, const unsigned short* __restrict__ W3,
    unsigned short* __restrict__ T, int K, int lda, int ldw)
{
  __shared__ unsigned short sA[3][128*32];
  __shared__ unsigned short sW1[3][128*32];
  __shared__ unsigned short sW3[3][128*32];
  int tid = threadIdx.x, lane = tid & 63, wave = tid >> 6;
  int wr = (wave >> 1)*64, wc = (wave & 1)*64;
  size_t bm = (size_t)blockIdx.x*128, bn = (size_t)blockIdx.y*128;
  int fr = lane & 15, q4 = lane >> 4, fq = q4*4;
  int lrow = lane >> 2;
  int gcol = ((lane & 3) ^ ((lrow >> 1) & 3)) * 8;

  f32x4 a1[4][4], a3[4][4];
  #pragma unroll
  for (int i = 0; i < 4; ++i)
    #pragma unroll
    for (int j = 0; j < 4; ++j) {
      a1[i][j] = (f32x4){0.f,0.f,0.f,0.f};
      a3[i][j] = (f32x4){0.f,0.f,0.f,0.f};
    }

  auto stage = [&](int buf, int kt) {   // 6 vmem ops per lane
    #pragma unroll
    for (int p = 0; p < 2; ++p) {
      int seg = wave*2 + p;
      size_t row = (size_t)(seg*16 + lrow);
      gload16(A  + (bm + row)*(size_t)lda + kt + gcol, &sA[buf][seg*512]);
      gload16(W1 + (bn + row)*(size_t)ldw + kt + gcol, &sW1[buf][seg*512]);
      gload16(W3 + (bn + row)*(size_t)ldw + kt + gcol, &sW3[buf][seg*512]);
    }
  };

  int nt = K >> 5;
  stage(0, 0);
  stage(1, 32);
  for (int t = 0; t < nt; ++t) {
    int cur = t % 3;
    if (t + 2 < nt) {
      stage((t+2)%3, (t+2)*32);
      asm volatile("s_waitcnt vmcnt(12)" ::: "memory");
    } else if (t + 1 < nt) {
      asm volatile("s_waitcnt vmcnt(6)" ::: "memory");
    } else {
      asm volatile("s_waitcnt vmcnt(0)" ::: "memory");
    }
    __builtin_amdgcn_sched_barrier(0);
    __builtin_amdgcn_s_barrier();          // A: buf[cur] fully staged
    __builtin_amdgcn_sched_barrier(0);
    s16x8 af[4], b1[4], b3[4];
    #pragma unroll
    for (int i = 0; i < 4; ++i) {
      int ra = wr + i*16 + fr, rb = wc + i*16 + fr;
      af[i] = *(const s16x8*)((const char*)&sA[cur][0]  + ra*64 + ((q4 ^ ((ra>>1)&3)) << 4));
      b1[i] = *(const s16x8*)((const char*)&sW1[cur][0] + rb*64 + ((q4 ^ ((rb>>1)&3)) << 4));
      b3[i] = *(const s16x8*)((const char*)&sW3[cur][0] + rb*64 + ((q4 ^ ((rb>>1)&3)) << 4));
    }
    __builtin_amdgcn_s_setprio(1);
    #pragma unroll
    for (int i = 0; i < 4; ++i)
      #pragma unroll
      for (int j = 0; j < 4; ++j) {
        a1[i][j] = __builtin_amdgcn_mfma_f32_16x16x32_bf16(af[i], b1[j], a1[i][j], 0, 0, 0);
        a3[i][j] = __builtin_amdgcn_mfma_f32_16x16x32_bf16(af[i], b3[j], a3[i][j], 0, 0, 0);
      }
    __builtin_amdgcn_s_setprio(0);
    __builtin_amdgcn_sched_barrier(0);
    __builtin_amdgcn_s_barrier();          // B: all reads of buf[cur] retired
    __builtin_amdgcn_sched_barrier(0);
  }

  #pragma unroll
  for (int i = 0; i < 4; ++i)
    #pragma unroll
    for (int j = 0; j < 4; ++j) {
      size_t row0 = bm + wr + i*16 + fq;
      size_t col  = bn + wc + j*16 + fr;
      #pragma unroll
      for (int qi = 0; qi < 4; ++qi) {
        float u = a1[i][j][qi];
        float g = a3[i][j][qi];
        float su = u / (1.0f + __expf(-u));
        T[(row0 + qi)*(size_t)FF_ + col] = f2bf(su * g);
      }
    }
}

// ===== generic GEMM: 128x64, BK=32, depth-2 pipeline, 2 barriers/step =========
// EPI: 0 = store f32, 3 = rope->bf16, 4 = bf16
template<int EPI>
__device__ __forceinline__ void gemm64_core(
    const unsigned short* __restrict__ A, const unsigned short* __restrict__ W,
    float* __restrict__ Cf, unsigned short* __restrict__ Cb,
    int kbase, int Kslice, int lda, int ldw, int ldc,
    const float* __restrict__ costab, const float* __restrict__ sintab)
{
  __shared__ unsigned short sA[3][128*32];
  __shared__ unsigned short sW[3][64*32];
  int tid = threadIdx.x, lane = tid & 63, wave = tid >> 6;
  int wr = (wave >> 1)*64, wc = (wave & 1)*32;
  size_t bm = (size_t)blockIdx.x*128, bn = (size_t)blockIdx.y*64;
  int fr = lane & 15, q4 = lane >> 4, fq = q4*4;
  int lrow = lane >> 2;
  int gcol = ((lane & 3) ^ ((lrow >> 1) & 3)) * 8;

  f32x4 acc[4][2];
  #pragma unroll
  for (int i = 0; i < 4; ++i) {
    acc[i][0] = (f32x4){0.f,0.f,0.f,0.f};
    acc[i][1] = (f32x4){0.f,0.f,0.f,0.f};
  }

  auto stage = [&](int buf, int kt) {   // 3 vmem ops per lane
    #pragma unroll
    for (int p = 0; p < 2; ++p) {
      int seg = wave*2 + p;
      gload16(A + (bm + seg*16 + lrow)*(size_t)lda + kt + gcol, &sA[buf][seg*512]);
    }
    gload16(W + (bn + wave*16 + lrow)*(size_t)ldw + kt + gcol, &sW[buf][wave*512]);
  };

  int nt = Kslice >> 5;
  stage(0, kbase);
  stage(1, kbase + 32);
  for (int t = 0; t < nt; ++t) {
    int cur = t % 3;
    if (t + 2 < nt) {
      stage((t+2)%3, kbase + (t+2)*32);
      asm volatile("s_waitcnt vmcnt(6)" ::: "memory");
    } else if (t + 1 < nt) {
      asm volatile("s_waitcnt vmcnt(3)" ::: "memory");
    } else {
      asm volatile("s_waitcnt vmcnt(0)" ::: "memory");
    }
    __builtin_amdgcn_sched_barrier(0);
    __builtin_amdgcn_s_barrier();          // A: buf[cur] fully staged
    __builtin_amdgcn_sched_barrier(0);
    s16x8 af[4], bw[2];
    #pragma unroll
    for (int i = 0; i < 4; ++i) {
      int r = wr + i*16 + fr;
      af[i] = *(const s16x8*)((const char*)&sA[cur][0] + r*64 + ((q4 ^ ((r>>1)&3)) << 4));
    }
    #pragma unroll
    for (int j = 0; j < 2; ++j) {
      int r = wc + j*16 + fr;
      bw[j] = *(const s16x8*)((const char*)&sW[cur][0] + r*64 + ((q4 ^ ((r>>1)&3)) << 4));
    }
    __builtin_amdgcn_s_setprio(1);
    #pragma unroll
    for (int i = 0; i < 4; ++i)
      #pragma unroll
      for (int j = 0; j < 2; ++j)
        acc[i][j] = __builtin_amdgcn_mfma_f32_16x16x32_bf16(af[i], bw[j], acc[i][j], 0, 0, 0);
    __builtin_amdgcn_s_setprio(0);
    __builtin_amdgcn_sched_barrier(0);
    __builtin_amdgcn_s_barrier();          // B: all reads of buf[cur] retired
    __builtin_amdgcn_sched_barrier(0);
  }

  #pragma unroll
  for (int i = 0; i < 4; ++i)
    #pragma unroll
    for (int j = 0; j < 2; ++j) {
      size_t row0 = bm + wr + i*16 + fq;
      size_t col  = bn + wc + j*16 + fr;
      #pragma unroll
      for (int qi = 0; qi < 4; ++qi) {
        float val = acc[i][j][qi];
        size_t idx = (row0 + qi)*(size_t)ldc + col;
        if (EPI == 3) {
          float pv = __shfl_xor(val, 1, 64);
          int srow = (int)((row0 + qi) & 1023);
          int d = (int)(col & 63);
          float cs = costab[srow*64 + d];
          float sn = sintab[srow*64 + d];
          Cb[idx] = f2bf(val*cs + ((d & 1) ? pv : -pv)*sn);
        } else if (EPI == 4) {
          Cb[idx] = f2bf(val);
        } else {
          Cf[idx] = val;
        }
      }
    }
}

template<int EPI>
__global__ __launch_bounds__(256, 3) void gemm64(
    const unsigned short* __restrict__ A, const unsigned short* __restrict__ W,
    float* __restrict__ Cf, int K, int lda, int ldw, int ldc)
{
  gemm64_core<EPI>(A, W, Cf, nullptr, 0, K, lda, ldw, ldc, nullptr, nullptr);
}

// split-K: blockIdx.z = k-slice; writes partial C to P + z*(B*S*ldc)
__global__ __launch_bounds__(256, 3) void gemm64_ksplit(
    const unsigned short* __restrict__ A, const unsigned short* __restrict__ W,
    float* __restrict__ P, int Kslice, int lda, int ldw, int ldc)
{
  float* out = P + (size_t)blockIdx.z * (size_t)B_ * S_ * ldc;
  gemm64_core<0>(A, W, out, nullptr, blockIdx.z*Kslice, Kslice, lda, ldw, ldc,
                 nullptr, nullptr);
}

__global__ __launch_bounds__(256, 3) void gemm_qkv64(
    const unsigned short* __restrict__ A,
    const unsigned short* __restrict__ Wq, const unsigned short* __restrict__ Wk,
    const unsigned short* __restrict__ Wv,
    unsigned short* __restrict__ Cq, unsigned short* __restrict__ Ck,
    unsigned short* __restrict__ Cv,
    const float* __restrict__ costab, const float* __restrict__ sintab)
{
  if (blockIdx.z == 0)
    gemm64_core<3>(A, Wq, nullptr, Cq, 0, D_, D_, D_, D_, costab, sintab);
  else if (blockIdx.z == 1)
    gemm64_core<3>(A, Wk, nullptr, Ck, 0, D_, D_, D_, D_, costab, sintab);
  else
    gemm64_core<4>(A, Wv, nullptr, Cv, 0, D_, D_, D_, D_, nullptr, nullptr);
}

// ---------------- host launcher -----------------------------------------------
extern "C" void kernel_launch(void* const* d_in, const int* in_sizes, int n_in,
                              void* d_out, int out_size, void* d_ws, size_t ws_size,
                              hipStream_t stream)
{
  const int*   tokens    = (const int*)d_in[0];
  const int*   mood      = (const int*)d_in[1];
  const int*   raga      = (const int*)d_in[2];
  const int*   taal      = (const int*)d_in[3];
  const float* tempo     = (const float*)d_in[4];
  const float* duration  = (const float*)d_in[5];
  const int*   tcl       = (const int*)d_in[6];
  const float* tok_emb   = (const float*)d_in[7];
  const float* mood_emb  = (const float*)d_in[8];
  const float* raga_emb  = (const float*)d_in[9];
  const float* taal_emb  = (const float*)d_in[10];
  const float* tempo_w   = (const float*)d_in[11];
  const float* tempo_b   = (const float*)d_in[12];
  const float* dur_w     = (const float*)d_in[13];
  const float* dur_b     = (const float*)d_in[14];
  const float* proj_w    = (const float*)d_in[15];
  const float* proj_b    = (const float*)d_in[16];
  const float* ln_g      = (const float*)d_in[17];
  const float* ln_b      = (const float*)d_in[18];
  const float* cycle_emb = (const float*)d_in[19];
  const float* strength_e= (const float*)d_in[20];
  const float* l_anorm   = (const float*)d_in[21];
  const float* l_fnorm   = (const float*)d_in[22];
  const float* l_q       = (const float*)d_in[23];
  const float* l_k       = (const float*)d_in[24];
  const float* l_v       = (const float*)d_in[25];
  const float* l_o       = (const float*)d_in[26];
  const float* l_w1      = (const float*)d_in[27];
  const float* l_w2      = (const float*)d_in[28];
  const float* l_w3      = (const float*)d_in[29];
  const float* final_norm= (const float*)d_in[30];
  const float* head_w    = (const float*)d_in[31];

  size_t off = 0;
  char* wsb = (char*)d_ws;
  auto alloc = [&](size_t bytes) -> char* {
    char* p = wsb + off;
    off += (bytes + 255) & ~(size_t)255;
    return p;
  };
  float*          condb  = (float*)alloc((size_t)B_*D_*4);
  float*          costab = (float*)alloc((size_t)S_*HD_*4);
  float*          sintab = (float*)alloc((size_t)S_*HD_*4);
  float*          x      = (float*)alloc((size_t)B_*S_*D_*4);
  unsigned short* hbuf   = (unsigned short*)alloc((size_t)B_*S_*D_*2);
  unsigned short* qb     = (unsigned short*)alloc((size_t)B_*S_*D_*2);
  unsigned short* kb     = (unsigned short*)alloc((size_t)B_*S_*D_*2);
  unsigned short* vb     = (unsigned short*)alloc((size_t)B_*S_*D_*2);
  unsigned short* yb     = (unsigned short*)alloc((size_t)B_*S_*D_*2);
  unsigned short* tb     = (unsigned short*)alloc((size_t)B_*S_*FF_*2);
  float*          pbuf   = (float*)alloc((size_t)4*B_*S_*D_*4);   // split-K partials

  const size_t N_QKVO = (size_t)L_*D_*D_;
  const size_t N_FF   = (size_t)L_*FF_*D_;
  const size_t N_HEAD = (size_t)V_*D_;
  const size_t W_TOT  = 4*N_QKVO + 3*N_FF + N_HEAD;
  unsigned short* wbf = (unsigned short*)alloc(W_TOT*2);
  unsigned short* bq = wbf;
  unsigned short* bk = wbf + N_QKVO;
  unsigned short* bv = wbf + 2*N_QKVO;
  unsigned short* bo = wbf + 3*N_QKVO;
  unsigned short* b1 = wbf + 4*N_QKVO;
  unsigned short* b2 = wbf + 4*N_QKVO + N_FF;
  unsigned short* b3 = wbf + 4*N_QKVO + 2*N_FF;
  unsigned short* bh = wbf + 4*N_QKVO + 3*N_FF;

  rope_table_kernel<<<(S_*HD_)/256, 256, 0, stream>>>(costab, sintab);
  cond_kernel<<<B_, 256, 0, stream>>>(mood, raga, taal, tempo, duration,
      mood_emb, raga_emb, taal_emb, tempo_w, tempo_b, dur_w, dur_b,
      proj_w, proj_b, ln_g, ln_b, condb);
  embed_kernel<<<B_*S_, 256, 0, stream>>>(tokens, tok_emb, condb, cycle_emb,
      strength_e, tcl, x);

  // one grid-stride launch converts all weights (~2048 resident blocks)
  cvt_all_kernel<<<2048, 256, 0, stream>>>(
      l_q, l_k, l_v, l_o, l_w1, l_w2, l_w3, head_w, wbf);

  const int rows = B_*S_;   // 2048
  rmsnorm_kernel<<<rows, 256, 0, stream>>>(x, l_anorm, hbuf);
  for (int l = 0; l < L_; ++l) {
    size_t dd = (size_t)l*D_*D_;
    size_t fd = (size_t)l*FF_*D_;
    gemm_qkv64<<<dim3(rows/128, D_/64, 3), 256, 0, stream>>>(
        hbuf, bq + dd, bk + dd, bv + dd, qb, kb, vb, costab, sintab);
    attn_mfma<<<dim3(S_/64, H_, B_), 256, 0, stream>>>(qb, kb, vb, yb);
    gemm64_ksplit<<<dim3(rows/128, D_/64, 2), 256, 0, stream>>>(
        yb, bo + dd, pbuf, 512, D_, D_, D_);
    resid_rmsnorm_kernel<<<rows, 256, 0, stream>>>(
        x, pbuf, 2, l_fnorm + (size_t)l*D_, hbuf);
    gemm_w13<<<dim3(rows/128, FF_/128), 256, 0, stream>>>(
        hbuf, b1 + fd, b3 + fd, tb, D_, D_, D_);
    gemm64_ksplit<<<dim3(rows/128, D_/64, 4), 256, 0, stream>>>(
        tb, b2 + fd, pbuf, 1024, FF_, FF_, D_);
    const float* nextw = (l+1 < L_) ? (l_anorm + (size_t)(l+1)*D_) : final_norm;
    resid_rmsnorm_kernel<<<rows, 256, 0, stream>>>(x, pbuf, 4, nextw, hbuf);
  }
  gemm64<0><<<dim3(rows/128, V_/64), 256, 0, stream>>>(
      hbuf, bh, (float*)d_out, D_, D_, D_, V_);
}

// Round 12
// 1563.161 us; speedup vs baseline: 1.0210x; 1.0210x over previous
//
#include <hip/hip_runtime.h>
#include <math.h>

#define D_ 1024
#define H_ 16
#define HD_ 64
#define L_ 8
#define V_ 2048
#define FF_ 4096
#define WIN_ 256
#define B_ 2
#define S_ 1024
#define MAXCYC_ 16

typedef __attribute__((ext_vector_type(4))) float f32x4;
typedef __attribute__((ext_vector_type(8))) short s16x8;

__device__ __forceinline__ unsigned short f2bf(float f) {
  union { float f; unsigned int u; } v; v.f = f;
  unsigned int r = v.u + 0x7FFFu + ((v.u >> 16) & 1u);
  return (unsigned short)(r >> 16);
}

__device__ __forceinline__ float wave_sum(float v) {
  #pragma unroll
  for (int m = 1; m < 64; m <<= 1) v += __shfl_xor(v, m, 64);
  return v;
}

// async global->LDS, 16B per lane. dst wave-uniform base; HW writes dst+lane*16.
__device__ __forceinline__ void gload16(const unsigned short* g, unsigned short* lds) {
  __builtin_amdgcn_global_load_lds(
      (const __attribute__((address_space(1))) void*)g,
      (__attribute__((address_space(3))) void*)lds,
      16, 0, 0);
}

// XCD-chunked block swizzle (requires total blocks % 8 == 0). Pure permutation:
// consecutive swizzled ids stay on one XCD -> weight panels L2-resident per XCD.
__device__ __forceinline__ void xcd_swz(int& bx, int& by, int& bz) {
  int gx = gridDim.x, gy = gridDim.y;
  int tot = gx * gy * (int)gridDim.z;
  int bid = (int)blockIdx.x + gx*((int)blockIdx.y + gy*(int)blockIdx.z);
  int cpx = tot >> 3;
  int swz = (bid & 7)*cpx + (bid >> 3);
  bx = swz % gx;
  int r = swz / gx;
  by = r % gy;
  bz = r / gy;
}

// ---------------- f32 -> bf16 convert, ALL weights in one launch --------------
// (round-10 measured-best form: one-shot blocks, ushort4 pair stores)
__global__ __launch_bounds__(256) void cvt_all_kernel(
    const float* __restrict__ s0, const float* __restrict__ s1,
    const float* __restrict__ s2, const float* __restrict__ s3,
    const float* __restrict__ s4, const float* __restrict__ s5,
    const float* __restrict__ s6, const float* __restrict__ s7,
    unsigned short* __restrict__ dst)
{
  const long nq = (long)L_*D_*D_/8;      // 1,048,576 chunks of 8
  const long nf = (long)L_*FF_*D_/8;     // 4,194,304
  const long nh = (long)V_*D_/8;         // 262,144
  const long tot = 4*nq + 3*nf + nh;
  long i = (long)blockIdx.x*256 + threadIdx.x;
  if (i >= tot) return;
  const float* src;
  long off = i;
  if (off < nq)              { src = s0; }
  else if ((off -= nq) < nq) { src = s1; }
  else if ((off -= nq) < nq) { src = s2; }
  else if ((off -= nq) < nq) { src = s3; }
  else if ((off -= nq) < nf) { src = s4; }
  else if ((off -= nf) < nf) { src = s5; }
  else if ((off -= nf) < nf) { src = s6; }
  else { off -= nf;            src = s7; }
  const float4* s = (const float4*)src + off*2;
  float4 a = s[0], b = s[1];
  ushort4 lo, hi;
  lo.x = f2bf(a.x); lo.y = f2bf(a.y); lo.z = f2bf(a.z); lo.w = f2bf(a.w);
  hi.x = f2bf(b.x); hi.y = f2bf(b.y); hi.z = f2bf(b.z); hi.w = f2bf(b.w);
  *(ushort4*)(dst + i*8)     = lo;
  *(ushort4*)(dst + i*8 + 4) = hi;
}

// ---------------- conditioning ----------------------------------------------
__global__ __launch_bounds__(256) void cond_kernel(
    const int* mood, const int* raga, const int* taal,
    const float* tempo, const float* duration,
    const float* mood_emb, const float* raga_emb, const float* taal_emb,
    const float* tempo_w, const float* tempo_b, const float* dur_w, const float* dur_b,
    const float* proj_w, const float* proj_b, const float* ln_g, const float* ln_b,
    float* cond)
{
  int b = blockIdx.x;
  int t = threadIdx.x;
  __shared__ float feat[192];
  __shared__ float red[4];
  if (t < 64)        feat[t] = mood_emb[mood[b]*64 + t];
  else if (t < 128)  feat[t] = raga_emb[raga[b]*64 + (t-64)];
  else if (t < 160)  feat[t] = taal_emb[taal[b]*32 + (t-128)];
  else if (t < 176)  feat[t] = tempo[b]*tempo_w[t-160] + tempo_b[t-160];
  else if (t < 192)  feat[t] = duration[b]*dur_w[t-176] + dur_b[t-176];
  __syncthreads();
  float g[4];
  #pragma unroll
  for (int r = 0; r < 4; ++r) {
    int j = t + 256*r;
    const float* w = proj_w + (size_t)j*192;
    float acc = proj_b[j];
    for (int f = 0; f < 192; ++f) acc += feat[f]*w[f];
    g[r] = 0.5f * acc * (1.0f + erff(acc * 0.7071067811865475f));
  }
  int lane = t & 63, wv = t >> 6;
  float s1 = g[0]+g[1]+g[2]+g[3];
  s1 = wave_sum(s1);
  if (lane == 0) red[wv] = s1;
  __syncthreads();
  float mu = (red[0]+red[1]+red[2]+red[3]) * (1.0f/1024.0f);
  __syncthreads();
  float vs = 0.f;
  #pragma unroll
  for (int r = 0; r < 4; ++r) { float d = g[r]-mu; vs += d*d; }
  vs = wave_sum(vs);
  if (lane == 0) red[wv] = vs;
  __syncthreads();
  float var = (red[0]+red[1]+red[2]+red[3]) * (1.0f/1024.0f);
  float is = rsqrtf(var + 1e-5f);
  #pragma unroll
  for (int r = 0; r < 4; ++r) {
    int j = t + 256*r;
    cond[(size_t)b*D_ + j] = (g[r]-mu)*is*ln_g[j] + ln_b[j];
  }
}

// ---------------- embedding sum ----------------------------------------------
__global__ __launch_bounds__(256) void embed_kernel(
    const int* tokens, const float* tok_emb, const float* cond,
    const float* cycle_emb, const float* strength_emb, const int* tcl_p, float* x)
{
  int row = blockIdx.x;
  int b = row >> 10, s = row & 1023;
  int tcl = tcl_p[0];
  int cyc = tcl < MAXCYC_ ? tcl : MAXCYC_;
  int pr  = s % cyc;
  int str = (s % tcl == 0) ? 0 : 3;
  int tok = tokens[row];
  int d = threadIdx.x * 4;
  float4 a = *(const float4*)&tok_emb[(size_t)tok*D_ + d];
  float4 c = *(const float4*)&cond[(size_t)b*D_ + d];
  float4 p = *(const float4*)&cycle_emb[(size_t)pr*D_ + d];
  float4 e = *(const float4*)&strength_emb[(size_t)str*D_ + d];
  float4 o; o.x=a.x+c.x+p.x+e.x; o.y=a.y+c.y+p.y+e.y; o.z=a.z+c.z+p.z+e.z; o.w=a.w+c.w+p.w+e.w;
  *(float4*)&x[(size_t)row*D_ + d] = o;
}

// ---------------- rmsnorm -> bf16 --------------------------------------------
__global__ __launch_bounds__(256) void rmsnorm_kernel(
    const float* x, const float* w, unsigned short* out)
{
  int row = blockIdx.x;
  int t = threadIdx.x;
  __shared__ float red[4];
  const float* xr = x + (size_t)row*D_;
  float4 v = *(const float4*)&xr[t*4];
  float ss = v.x*v.x + v.y*v.y + v.z*v.z + v.w*v.w;
  ss = wave_sum(ss);
  int lane = t & 63, wv = t >> 6;
  if (lane == 0) red[wv] = ss;
  __syncthreads();
  float total = red[0]+red[1]+red[2]+red[3];
  float scale = rsqrtf(total * (1.0f/1024.0f) + 1e-5f);
  float4 wv4 = *(const float4*)&w[t*4];
  ushort4 o;
  o.x = f2bf(wv4.x * v.x * scale);
  o.y = f2bf(wv4.y * v.y * scale);
  o.z = f2bf(wv4.z * v.z * scale);
  o.w = f2bf(wv4.w * v.w * scale);
  *(ushort4*)&out[(size_t)row*D_ + t*4] = o;
}

// -------- fused: x += sum(partials); rmsnorm(x) -> bf16 -----------------------
__global__ __launch_bounds__(256) void resid_rmsnorm_kernel(
    float* __restrict__ x, const float* __restrict__ part, int nparts,
    const float* __restrict__ w, unsigned short* __restrict__ out)
{
  int row = blockIdx.x;
  int t = threadIdx.x;
  __shared__ float red[4];
  size_t base = (size_t)row*D_ + t*4;
  const size_t pstride = (size_t)B_*S_*D_;
  float4 v = *(const float4*)&x[base];
  for (int p = 0; p < nparts; ++p) {
    float4 a = *(const float4*)&part[p*pstride + base];
    v.x += a.x; v.y += a.y; v.z += a.z; v.w += a.w;
  }
  *(float4*)&x[base] = v;
  float ss = v.x*v.x + v.y*v.y + v.z*v.z + v.w*v.w;
  ss = wave_sum(ss);
  int lane = t & 63, wv = t >> 6;
  if (lane == 0) red[wv] = ss;
  __syncthreads();
  float total = red[0]+red[1]+red[2]+red[3];
  float scale = rsqrtf(total * (1.0f/1024.0f) + 1e-5f);
  float4 wv4 = *(const float4*)&w[t*4];
  ushort4 o;
  o.x = f2bf(wv4.x * v.x * scale);
  o.y = f2bf(wv4.y * v.y * scale);
  o.z = f2bf(wv4.z * v.z * scale);
  o.w = f2bf(wv4.w * v.w * scale);
  *(ushort4*)&out[(size_t)row*D_ + t*4] = o;
}

// ---------------- rope tables -------------------------------------------------
__global__ __launch_bounds__(256) void rope_table_kernel(float* costab, float* sintab)
{
  int i = blockIdx.x*256 + threadIdx.x;
  int s = i >> 6, d = i & 63;
  float inv = powf(10000.0f, -(float)(d & 31) * (1.0f/32.0f));
  float ang = (float)s * inv;
  float sn, cs;
  sincosf(ang, &sn, &cs);
  costab[i] = cs; sintab[i] = sn;
}

// =============== MFMA sliding-window flash attention (QBLK=64) =================
__global__ __launch_bounds__(256) void attn_mfma(
    const unsigned short* __restrict__ q, const unsigned short* __restrict__ k,
    const unsigned short* __restrict__ v, unsigned short* __restrict__ y)
{
  __shared__ unsigned short Ks[64*64];     // [key][d], 128B rows, chunk-swizzled
  __shared__ unsigned short VsT[64*72];    // [d][key], ld=72
  __shared__ unsigned short Ps[4*16*72];   // per-wave P / output tile

  int qb0 = blockIdx.x * 64;
  int h = blockIdx.y, b = blockIdx.z;
  int t = threadIdx.x, lane = t & 63, wv = t >> 6;
  int c = lane & 15, q4 = lane >> 4;
  unsigned short* Pw = &Ps[wv*16*72];

  s16x8 aq[2];
  {
    const unsigned short* qp =
        q + ((size_t)(b*S_ + qb0 + wv*16 + c)*D_ + h*HD_ + q4*8);
    aq[0] = *(const s16x8*)qp;
    aq[1] = *(const s16x8*)(qp + 32);
  }

  f32x4 o[4];
  #pragma unroll
  for (int j = 0; j < 4; ++j) o[j] = (f32x4){0.f,0.f,0.f,0.f};
  float m[4] = {-1e30f,-1e30f,-1e30f,-1e30f};
  float l[4] = {0.f,0.f,0.f,0.f};

  int skey = t >> 2;
  int scol = (t & 3) * 16;
  int kt0 = qb0 - 256; if (kt0 < 0) kt0 = 0;

  for (int kt = kt0; kt <= qb0; kt += 64) {
    __syncthreads();
    {
      const unsigned short* kp = k + ((size_t)(b*S_ + kt + skey)*D_ + h*HD_ + scol);
      s16x8 k0 = *(const s16x8*)kp;
      s16x8 k1 = *(const s16x8*)(kp + 8);
      int ch0 = scol >> 3;
      *(s16x8*)((char*)Ks + skey*128 + ((ch0 ^ (skey & 7)) << 4)) = k0;
      *(s16x8*)((char*)Ks + skey*128 + (((ch0+1) ^ (skey & 7)) << 4)) = k1;
      const unsigned short* vp = v + ((size_t)(b*S_ + kt + skey)*D_ + h*HD_ + scol);
      s16x8 v0 = *(const s16x8*)vp;
      s16x8 v1 = *(const s16x8*)(vp + 8);
      #pragma unroll
      for (int i = 0; i < 8; ++i) {
        VsT[(scol + i)*72 + skey]     = (unsigned short)v0[i];
        VsT[(scol + 8 + i)*72 + skey] = (unsigned short)v1[i];
      }
    }
    __syncthreads();

    f32x4 sa[4];
    #pragma unroll
    for (int j = 0; j < 4; ++j) sa[j] = (f32x4){0.f,0.f,0.f,0.f};
    __builtin_amdgcn_s_setprio(1);
    #pragma unroll
    for (int ks = 0; ks < 2; ++ks)
      #pragma unroll
      for (int j = 0; j < 4; ++j) {
        int key = j*16 + c;
        s16x8 bk = *(const s16x8*)((const char*)Ks + key*128 +
                                   (((q4 + ks*4) ^ (key & 7)) << 4));
        sa[j] = __builtin_amdgcn_mfma_f32_16x16x32_bf16(aq[ks], bk, sa[j], 0, 0, 0);
      }
    __builtin_amdgcn_s_setprio(0);

    float sv[4][4];
    #pragma unroll
    for (int j = 0; j < 4; ++j) {
      int kg = kt + j*16 + c;
      #pragma unroll
      for (int reg = 0; reg < 4; ++reg) {
        int qg = qb0 + wv*16 + q4*4 + reg;
        bool ok = (qg >= kg) && (qg - kg < WIN_);
        sv[j][reg] = ok ? sa[j][reg]*0.125f : -3e38f;
      }
    }
    #pragma unroll
    for (int reg = 0; reg < 4; ++reg) {
      float mx = fmaxf(fmaxf(sv[0][reg], sv[1][reg]), fmaxf(sv[2][reg], sv[3][reg]));
      #pragma unroll
      for (int msk = 1; msk < 16; msk <<= 1)
        mx = fmaxf(mx, __shfl_xor(mx, msk, 64));
      float nm = fmaxf(m[reg], mx);
      float f = __expf(m[reg] - nm);
      m[reg] = nm;
      l[reg] *= f;
      o[0][reg] *= f; o[1][reg] *= f; o[2][reg] *= f; o[3][reg] *= f;
      float ps = 0.f;
      #pragma unroll
      for (int j = 0; j < 4; ++j) {
        float p = __expf(sv[j][reg] - nm);
        ps += p;
        Pw[(q4*4 + reg)*72 + j*16 + c] = f2bf(p);
      }
      l[reg] += ps;
    }

    __builtin_amdgcn_s_setprio(1);
    #pragma unroll
    for (int ks = 0; ks < 2; ++ks) {
      s16x8 pa = *(const s16x8*)((const char*)Pw + c*144 + (q4 + ks*4)*16);
      #pragma unroll
      for (int j = 0; j < 4; ++j) {
        s16x8 bv = *(const s16x8*)((const char*)VsT + (j*16 + c)*144 + (q4 + ks*4)*16);
        o[j] = __builtin_amdgcn_mfma_f32_16x16x32_bf16(pa, bv, o[j], 0, 0, 0);
      }
    }
    __builtin_amdgcn_s_setprio(0);
  }

  float inv[4];
  #pragma unroll
  for (int reg = 0; reg < 4; ++reg) {
    float ll = l[reg];
    #pragma unroll
    for (int msk = 1; msk < 16; msk <<= 1) ll += __shfl_xor(ll, msk, 64);
    inv[reg] = 1.0f / ll;
  }
  #pragma unroll
  for (int j = 0; j < 4; ++j)
    #pragma unroll
    for (int reg = 0; reg < 4; ++reg)
      Pw[(q4*4 + reg)*72 + j*16 + c] = f2bf(o[j][reg] * inv[reg]);
  int lr = lane >> 2, cc = (lane & 3)*16;
  s16x8 y0 = *(const s16x8*)((const char*)Pw + lr*144 + cc*2);
  s16x8 y1 = *(const s16x8*)((const char*)Pw + lr*144 + cc*2 + 16);
  unsigned short* yp = y + ((size_t)(b*S_ + qb0 + wv*16 + lr)*D_ + h*HD_ + cc);
  *(s16x8*)yp = y0;
  *(s16x8*)(yp + 8) = y1;
}

// ===== fused W1/W3 GEMM: 128x128, BK=32, depth-2 pipeline, 2 barriers/step ====
__global__ __launch_bounds__(256, 2) void gemm_w13(
    const unsigned short* __restrict__ A,
    const unsigned short* __restrict__ W1, const unsigned short* __restrict__ W3,
    unsigned short* __restrict__ T, int K, int lda, int ldw)
{
  __shared__ unsigned short sA[3][128*32];
  __shared__ unsigned short sW1[3][128*32];
  __shared__ unsigned short sW3[3][128*32];
  int bx, by, bz;
  xcd_swz(bx, by, bz);
  int tid = threadIdx.x, lane = tid & 63, wave = tid >> 6;
  int wr = (wave >> 1)*64, wc = (wave & 1)*64;
  size_t bm = (size_t)bx*128, bn = (size_t)by*128;
  int fr = lane & 15, q4 = lane >> 4, fq = q4*4;
  int lrow = lane >> 2;
  int gcol = ((lane & 3) ^ ((lrow >> 1) & 3)) * 8;

  f32x4 a1[4][4], a3[4][4];
  #pragma unroll
  for (int i = 0; i < 4; ++i)
    #pragma unroll
    for (int j = 0; j < 4; ++j) {
      a1[i][j] = (f32x4){0.f,0.f,0.f,0.f};
      a3[i][j] = (f32x4){0.f,0.f,0.f,0.f};
    }

  auto stage = [&](int buf, int kt) {   // 6 vmem ops per lane
    #pragma unroll
    for (int p = 0; p < 2; ++p) {
      int seg = wave*2 + p;
      size_t row = (size_t)(seg*16 + lrow);
      gload16(A  + (bm + row)*(size_t)lda + kt + gcol, &sA[buf][seg*512]);
      gload16(W1 + (bn + row)*(size_t)ldw + kt + gcol, &sW1[buf][seg*512]);
      gload16(W3 + (bn + row)*(size_t)ldw + kt + gcol, &sW3[buf][seg*512]);
    }
  };

  int nt = K >> 5;
  stage(0, 0);
  stage(1, 32);
  for (int t = 0; t < nt; ++t) {
    int cur = t % 3;
    if (t + 2 < nt) {
      stage((t+2)%3, (t+2)*32);
      asm volatile("s_waitcnt vmcnt(12)" ::: "memory");
    } else if (t + 1 < nt) {
      asm volatile("s_waitcnt vmcnt(6)" ::: "memory");
    } else {
      asm volatile("s_waitcnt vmcnt(0)" ::: "memory");
    }
    __builtin_amdgcn_sched_barrier(0);
    __builtin_amdgcn_s_barrier();          // A: buf[cur] fully staged
    __builtin_amdgcn_sched_barrier(0);
    s16x8 af[4], b1[4], b3[4];
    #pragma unroll
    for (int i = 0; i < 4; ++i) {
      int ra = wr + i*16 + fr, rb = wc + i*16 + fr;
      af[i] = *(const s16x8*)((const char*)&sA[cur][0]  + ra*64 + ((q4 ^ ((ra>>1)&3)) << 4));
      b1[i] = *(const s16x8*)((const char*)&sW1[cur][0] + rb*64 + ((q4 ^ ((rb>>1)&3)) << 4));
      b3[i] = *(const s16x8*)((const char*)&sW3[cur][0] + rb*64 + ((q4 ^ ((rb>>1)&3)) << 4));
    }
    __builtin_amdgcn_s_setprio(1);
    #pragma unroll
    for (int i = 0; i < 4; ++i)
      #pragma unroll
      for (int j = 0; j < 4; ++j) {
        a1[i][j] = __builtin_amdgcn_mfma_f32_16x16x32_bf16(af[i], b1[j], a1[i][j], 0, 0, 0);
        a3[i][j] = __builtin_amdgcn_mfma_f32_16x16x32_bf16(af[i], b3[j], a3[i][j], 0, 0, 0);
      }
    __builtin_amdgcn_s_setprio(0);
    __builtin_amdgcn_sched_barrier(0);
    __builtin_amdgcn_s_barrier();          // B: all reads of buf[cur] retired
    __builtin_amdgcn_sched_barrier(0);
  }

  #pragma unroll
  for (int i = 0; i < 4; ++i)
    #pragma unroll
    for (int j = 0; j < 4; ++j) {
      size_t row0 = bm + wr + i*16 + fq;
      size_t col  = bn + wc + j*16 + fr;
      #pragma unroll
      for (int qi = 0; qi < 4; ++qi) {
        float u = a1[i][j][qi];
        float g = a3[i][j][qi];
        float su = u / (1.0f + __expf(-u));
        T[(row0 + qi)*(size_t)FF_ + col] = f2bf(su * g);
      }
    }
}

// ===== generic GEMM: 128x64, BK=32, depth-2 pipeline, 2 barriers/step =========
// EPI: 0 = store f32, 3 = rope->bf16, 4 = bf16
template<int EPI>
__device__ __forceinline__ void gemm64_core(
    const unsigned short* __restrict__ A, const unsigned short* __restrict__ W,
    float* __restrict__ Cf, unsigned short* __restrict__ Cb,
    int bx, int by, int kbase, int Kslice, int lda, int ldw, int ldc,
    const float* __restrict__ costab, const float* __restrict__ sintab)
{
  __shared__ unsigned short sA[3][128*32];
  __shared__ unsigned short sW[3][64*32];
  int tid = threadIdx.x, lane = tid & 63, wave = tid >> 6;
  int wr = (wave >> 1)*64, wc = (wave & 1)*32;
  size_t bm = (size_t)bx*128, bn = (size_t)by*64;
  int fr = lane & 15, q4 = lane >> 4, fq = q4*4;
  int lrow = lane >> 2;
  int gcol = ((lane & 3) ^ ((lrow >> 1) & 3)) * 8;

  f32x4 acc[4][2];
  #pragma unroll
  for (int i = 0; i < 4; ++i) {
    acc[i][0] = (f32x4){0.f,0.f,0.f,0.f};
    acc[i][1] = (f32x4){0.f,0.f,0.f,0.f};
  }

  auto stage = [&](int buf, int kt) {   // 3 vmem ops per lane
    #pragma unroll
    for (int p = 0; p < 2; ++p) {
      int seg = wave*2 + p;
      gload16(A + (bm + seg*16 + lrow)*(size_t)lda + kt + gcol, &sA[buf][seg*512]);
    }
    gload16(W + (bn + wave*16 + lrow)*(size_t)ldw + kt + gcol, &sW[buf][wave*512]);
  };

  int nt = Kslice >> 5;
  stage(0, kbase);
  stage(1, kbase + 32);
  for (int t = 0; t < nt; ++t) {
    int cur = t % 3;
    if (t + 2 < nt) {
      stage((t+2)%3, kbase + (t+2)*32);
      asm volatile("s_waitcnt vmcnt(6)" ::: "memory");
    } else if (t + 1 < nt) {
      asm volatile("s_waitcnt vmcnt(3)" ::: "memory");
    } else {
      asm volatile("s_waitcnt vmcnt(0)" ::: "memory");
    }
    __builtin_amdgcn_sched_barrier(0);
    __builtin_amdgcn_s_barrier();          // A: buf[cur] fully staged
    __builtin_amdgcn_sched_barrier(0);
    s16x8 af[4], bw[2];
    #pragma unroll
    for (int i = 0; i < 4; ++i) {
      int r = wr + i*16 + fr;
      af[i] = *(const s16x8*)((const char*)&sA[cur][0] + r*64 + ((q4 ^ ((r>>1)&3)) << 4));
    }
    #pragma unroll
    for (int j = 0; j < 2; ++j) {
      int r = wc + j*16 + fr;
      bw[j] = *(const s16x8*)((const char*)&sW[cur][0] + r*64 + ((q4 ^ ((r>>1)&3)) << 4));
    }
    __builtin_amdgcn_s_setprio(1);
    #pragma unroll
    for (int i = 0; i < 4; ++i)
      #pragma unroll
      for (int j = 0; j < 2; ++j)
        acc[i][j] = __builtin_amdgcn_mfma_f32_16x16x32_bf16(af[i], bw[j], acc[i][j], 0, 0, 0);
    __builtin_amdgcn_s_setprio(0);
    __builtin_amdgcn_sched_barrier(0);
    __builtin_amdgcn_s_barrier();          // B: all reads of buf[cur] retired
    __builtin_amdgcn_sched_barrier(0);
  }

  #pragma unroll
  for (int i = 0; i < 4; ++i)
    #pragma unroll
    for (int j = 0; j < 2; ++j) {
      size_t row0 = bm + wr + i*16 + fq;
      size_t col  = bn + wc + j*16 + fr;
      #pragma unroll
      for (int qi = 0; qi < 4; ++qi) {
        float val = acc[i][j][qi];
        size_t idx = (row0 + qi)*(size_t)ldc + col;
        if (EPI == 3) {
          float pv = __shfl_xor(val, 1, 64);
          int srow = (int)((row0 + qi) & 1023);
          int d = (int)(col & 63);
          float cs = costab[srow*64 + d];
          float sn = sintab[srow*64 + d];
          Cb[idx] = f2bf(val*cs + ((d & 1) ? pv : -pv)*sn);
        } else if (EPI == 4) {
          Cb[idx] = f2bf(val);
        } else {
          Cf[idx] = val;
        }
      }
    }
}

template<int EPI>
__global__ __launch_bounds__(256, 3) void gemm64(
    const unsigned short* __restrict__ A, const unsigned short* __restrict__ W,
    float* __restrict__ Cf, int K, int lda, int ldw, int ldc)
{
  int bx, by, bz;
  xcd_swz(bx, by, bz);
  gemm64_core<EPI>(A, W, Cf, nullptr, bx, by, 0, K, lda, ldw, ldc, nullptr, nullptr);
}

// split-K: z-slice -> partial C at P + z*(B*S*ldc)
__global__ __launch_bounds__(256, 3) void gemm64_ksplit(
    const unsigned short* __restrict__ A, const unsigned short* __restrict__ W,
    float* __restrict__ P, int Kslice, int lda, int ldw, int ldc)
{
  int bx, by, bz;
  xcd_swz(bx, by, bz);
  float* out = P + (size_t)bz * (size_t)B_ * S_ * ldc;
  gemm64_core<0>(A, W, out, nullptr, bx, by, bz*Kslice, Kslice, lda, ldw, ldc,
                 nullptr, nullptr);
}

__global__ __launch_bounds__(256, 3) void gemm_qkv64(
    const unsigned short* __restrict__ A,
    const unsigned short* __restrict__ Wq, const unsigned short* __restrict__ Wk,
    const unsigned short* __restrict__ Wv,
    unsigned short* __restrict__ Cq, unsigned short* __restrict__ Ck,
    unsigned short* __restrict__ Cv,
    const float* __restrict__ costab, const float* __restrict__ sintab)
{
  int bx, by, bz;
  xcd_swz(bx, by, bz);
  if (bz == 0)
    gemm64_core<3>(A, Wq, nullptr, Cq, bx, by, 0, D_, D_, D_, D_, costab, sintab);
  else if (bz == 1)
    gemm64_core<3>(A, Wk, nullptr, Ck, bx, by, 0, D_, D_, D_, D_, costab, sintab);
  else
    gemm64_core<4>(A, Wv, nullptr, Cv, bx, by, 0, D_, D_, D_, D_, nullptr, nullptr);
}

// ---------------- host launcher -----------------------------------------------
extern "C" void kernel_launch(void* const* d_in, const int* in_sizes, int n_in,
                              void* d_out, int out_size, void* d_ws, size_t ws_size,
                              hipStream_t stream)
{
  const int*   tokens    = (const int*)d_in[0];
  const int*   mood      = (const int*)d_in[1];
  const int*   raga      = (const int*)d_in[2];
  const int*   taal      = (const int*)d_in[3];
  const float* tempo     = (const float*)d_in[4];
  const float* duration  = (const float*)d_in[5];
  const int*   tcl       = (const int*)d_in[6];
  const float* tok_emb   = (const float*)d_in[7];
  const float* mood_emb  = (const float*)d_in[8];
  const float* raga_emb  = (const float*)d_in[9];
  const float* taal_emb  = (const float*)d_in[10];
  const float* tempo_w   = (const float*)d_in[11];
  const float* tempo_b   = (const float*)d_in[12];
  const float* dur_w     = (const float*)d_in[13];
  const float* dur_b     = (const float*)d_in[14];
  const float* proj_w    = (const float*)d_in[15];
  const float* proj_b    = (const float*)d_in[16];
  const float* ln_g      = (const float*)d_in[17];
  const float* ln_b      = (const float*)d_in[18];
  const float* cycle_emb = (const float*)d_in[19];
  const float* strength_e= (const float*)d_in[20];
  const float* l_anorm   = (const float*)d_in[21];
  const float* l_fnorm   = (const float*)d_in[22];
  const float* l_q       = (const float*)d_in[23];
  const float* l_k       = (const float*)d_in[24];
  const float* l_v       = (const float*)d_in[25];
  const float* l_o       = (const float*)d_in[26];
  const float* l_w1      = (const float*)d_in[27];
  const float* l_w2      = (const float*)d_in[28];
  const float* l_w3      = (const float*)d_in[29];
  const float* final_norm= (const float*)d_in[30];
  const float* head_w    = (const float*)d_in[31];

  size_t off = 0;
  char* wsb = (char*)d_ws;
  auto alloc = [&](size_t bytes) -> char* {
    char* p = wsb + off;
    off += (bytes + 255) & ~(size_t)255;
    return p;
  };
  float*          condb  = (float*)alloc((size_t)B_*D_*4);
  float*          costab = (float*)alloc((size_t)S_*HD_*4);
  float*          sintab = (float*)alloc((size_t)S_*HD_*4);
  float*          x      = (float*)alloc((size_t)B_*S_*D_*4);
  unsigned short* hbuf   = (unsigned short*)alloc((size_t)B_*S_*D_*2);
  unsigned short* qb     = (unsigned short*)alloc((size_t)B_*S_*D_*2);
  unsigned short* kb     = (unsigned short*)alloc((size_t)B_*S_*D_*2);
  unsigned short* vb     = (unsigned short*)alloc((size_t)B_*S_*D_*2);
  unsigned short* yb     = (unsigned short*)alloc((size_t)B_*S_*D_*2);
  unsigned short* tb     = (unsigned short*)alloc((size_t)B_*S_*FF_*2);
  float*          pbuf   = (float*)alloc((size_t)4*B_*S_*D_*4);   // split-K partials

  const size_t N_QKVO = (size_t)L_*D_*D_;
  const size_t N_FF   = (size_t)L_*FF_*D_;
  const size_t N_HEAD = (size_t)V_*D_;
  const size_t W_TOT  = 4*N_QKVO + 3*N_FF + N_HEAD;
  unsigned short* wbf = (unsigned short*)alloc(W_TOT*2);
  unsigned short* bq = wbf;
  unsigned short* bk = wbf + N_QKVO;
  unsigned short* bv = wbf + 2*N_QKVO;
  unsigned short* bo = wbf + 3*N_QKVO;
  unsigned short* b1 = wbf + 4*N_QKVO;
  unsigned short* b2 = wbf + 4*N_QKVO + N_FF;
  unsigned short* b3 = wbf + 4*N_QKVO + 2*N_FF;
  unsigned short* bh = wbf + 4*N_QKVO + 3*N_FF;

  rope_table_kernel<<<(S_*HD_)/256, 256, 0, stream>>>(costab, sintab);
  cond_kernel<<<B_, 256, 0, stream>>>(mood, raga, taal, tempo, duration,
      mood_emb, raga_emb, taal_emb, tempo_w, tempo_b, dur_w, dur_b,
      proj_w, proj_b, ln_g, ln_b, condb);
  embed_kernel<<<B_*S_, 256, 0, stream>>>(tokens, tok_emb, condb, cycle_emb,
      strength_e, tcl, x);

  // one launch converts all weights (round-10 measured-best form)
  {
    long tot = (long)(W_TOT/8);
    int nblk = (int)((tot + 255) / 256);
    cvt_all_kernel<<<nblk, 256, 0, stream>>>(
        l_q, l_k, l_v, l_o, l_w1, l_w2, l_w3, head_w, wbf);
  }

  const int rows = B_*S_;   // 2048
  rmsnorm_kernel<<<rows, 256, 0, stream>>>(x, l_anorm, hbuf);
  for (int l = 0; l < L_; ++l) {
    size_t dd = (size_t)l*D_*D_;
    size_t fd = (size_t)l*FF_*D_;
    gemm_qkv64<<<dim3(rows/128, D_/64, 3), 256, 0, stream>>>(
        hbuf, bq + dd, bk + dd, bv + dd, qb, kb, vb, costab, sintab);
    attn_mfma<<<dim3(S_/64, H_, B_), 256, 0, stream>>>(qb, kb, vb, yb);
    gemm64_ksplit<<<dim3(rows/128, D_/64, 2), 256, 0, stream>>>(
        yb, bo + dd, pbuf, 512, D_, D_, D_);
    resid_rmsnorm_kernel<<<rows, 256, 0, stream>>>(
        x, pbuf, 2, l_fnorm + (size_t)l*D_, hbuf);
    gemm_w13<<<dim3(rows/128, FF_/128), 256, 0, stream>>>(
        hbuf, b1 + fd, b3 + fd, tb, D_, D_, D_);
    gemm64_ksplit<<<dim3(rows/128, D_/64, 4), 256, 0, stream>>>(
        tb, b2 + fd, pbuf, 1024, FF_, FF_, D_);
    const float* nextw = (l+1 < L_) ? (l_anorm + (size_t)(l+1)*D_) : final_norm;
    resid_rmsnorm_kernel<<<rows, 256, 0, stream>>>(x, pbuf, 4, nextw, hbuf);
  }
  gemm64<0><<<dim3(rows/128, V_/64), 256, 0, stream>>>(
      hbuf, bh, (float*)d_out, D_, D_, D_, V_);
}